// Round 3
// baseline (1465.534 us; speedup 1.0000x reference)
//
#include <hip/hip_runtime.h>

#define B_ 128
#define T_ 1024
#define I_ 128
#define H_ 256
#define O_ 64

// DPP row_ror:n control codes (rotate within row of 16 lanes)
#define ROR1 0x121
#define ROR2 0x122
#define ROR4 0x124
#define ROR8 0x128

template <int CTRL>
__device__ __forceinline__ float dpp_add(float x) {
    int xi = __float_as_int(x);
    int yi = __builtin_amdgcn_update_dpp(xi, xi, CTRL, 0xf, 0xf, false);
    return x + __int_as_float(yi);
}
// full sum across a row of 16 lanes; every lane ends with the total
__device__ __forceinline__ float reduce16(float x) {
    x = dpp_add<ROR1>(x);
    x = dpp_add<ROR2>(x);
    x = dpp_add<ROR4>(x);
    x = dpp_add<ROR8>(x);
    return x;
}
__device__ __forceinline__ float fma4(float4 w, float4 h, float a) {
    a = fmaf(w.x, h.x, a); a = fmaf(w.y, h.y, a);
    a = fmaf(w.z, h.z, a); a = fmaf(w.w, h.w, a);
    return a;
}

// ---------------------------------------------------------------------------
// Phase A: xw[row,j] = sum_i x[row,i]*W_xh[j,i] + b_h[j]
// 512 WGs x 256 thr (2 WG/CU). lane (jg=tid>>4, kb=tid&15) owns
// j in [jg*16,+16), k in [kb*8,+8) -> 128 VGPR weights. Per row: 2 ds_read_b128
// (own k-slice only), 128 fma, DPP rotate-reduce across the 16 kb lanes.
// kb==0 lanes store 16 results (+bias) to global. No LDS reduction phase.
// ---------------------------------------------------------------------------
__global__ __launch_bounds__(256, 2)
void xw_gemm_kernel(const float* __restrict__ x, const float* __restrict__ W_xh,
                    const float* __restrict__ b_h, float* __restrict__ xw)
{
    const int tid = threadIdx.x;
    const int kb  = tid & 15;
    const int jg  = tid >> 4;                       // 0..15
    __shared__ __align__(16) float xs[2][16 * I_];  // 2 x 8 KB

    float4 w[16][2];
#pragma unroll
    for (int a = 0; a < 16; ++a) {
        const float* wr = W_xh + (size_t)(jg * 16 + a) * I_ + kb * 8;
        w[a][0] = reinterpret_cast<const float4*>(wr)[0];
        w[a][1] = reinterpret_cast<const float4*>(wr)[1];
    }
    float4 bh[4];
#pragma unroll
    for (int c = 0; c < 4; ++c)
        bh[c] = reinterpret_cast<const float4*>(b_h + jg * 16)[c];

    const int base = blockIdx.x * 256;              // rows per WG = 256

    {   // stage tile 0 (16 rows x 128 floats = 8 KB)
        const float4* xp = reinterpret_cast<const float4*>(x + (size_t)base * I_);
        reinterpret_cast<float4*>(xs[0])[tid]       = xp[tid];
        reinterpret_cast<float4*>(xs[0])[tid + 256] = xp[tid + 256];
    }
    __syncthreads();

    int buf = 0;
    for (int tile = 0; tile < 16; ++tile) {
        float4 p0 = make_float4(0,0,0,0), p1 = make_float4(0,0,0,0);
        if (tile + 1 < 16) {
            const float4* xp = reinterpret_cast<const float4*>(
                x + (size_t)(base + (tile + 1) * 16) * I_);
            p0 = xp[tid]; p1 = xp[tid + 256];
        }
#pragma unroll 2
        for (int r = 0; r < 16; ++r) {
            const float4* xr = reinterpret_cast<const float4*>(
                xs[buf] + r * I_ + kb * 8);
            const float4 x0 = xr[0], x1 = xr[1];
            float acc[16];
#pragma unroll
            for (int a = 0; a < 16; ++a)
                acc[a] = fma4(w[a][1], x1, fma4(w[a][0], x0, 0.f));
#pragma unroll
            for (int a = 0; a < 16; ++a) acc[a] = reduce16(acc[a]);
            if (kb == 0) {
                float* orow = xw + (size_t)(base + tile * 16 + r) * H_ + jg * 16;
                reinterpret_cast<float4*>(orow)[0] =
                    make_float4(acc[0]+bh[0].x, acc[1]+bh[0].y, acc[2]+bh[0].z, acc[3]+bh[0].w);
                reinterpret_cast<float4*>(orow)[1] =
                    make_float4(acc[4]+bh[1].x, acc[5]+bh[1].y, acc[6]+bh[1].z, acc[7]+bh[1].w);
                reinterpret_cast<float4*>(orow)[2] =
                    make_float4(acc[8]+bh[2].x, acc[9]+bh[2].y, acc[10]+bh[2].z, acc[11]+bh[2].w);
                reinterpret_cast<float4*>(orow)[3] =
                    make_float4(acc[12]+bh[3].x, acc[13]+bh[3].y, acc[14]+bh[3].z, acc[15]+bh[3].w);
            }
        }
        if (tile + 1 < 16) {
            reinterpret_cast<float4*>(xs[buf ^ 1])[tid]       = p0;
            reinterpret_cast<float4*>(xs[buf ^ 1])[tid + 256] = p1;
        }
        __syncthreads();
        buf ^= 1;
    }
}

// ---------------------------------------------------------------------------
// Phase B: fused recurrence + out-projection, ONE barrier/step, DPP reduce.
// 128 WGs x 512 thr, one per batch row. lane (jg=tid>>4 in [0,32), kb=tid&15)
// owns W_hh rows j in [jg*8,+8) x k in [kb*16,+16) -> 128 VGPR, and
// W_out rows o in {jg*2,jg*2+1} x same k -> 32 VGPR.
// Step: hr(regs) -> 160 fma -> DPP rotate-reduce (all 16 kb lanes get full
// sums) -> kb==0 lanes: +xw, relu, 2x ds_write_b128 into double-buffered hs;
// out_{t-1} stored direct to global -> barrier -> all lanes reload their
// k-slice (4x ds_read_b128, chunk stride 36 floats -> 2-way banks = free).
// ---------------------------------------------------------------------------
__global__ __launch_bounds__(512, 1)
void rnn_scan_kernel(const float* __restrict__ xw, const float* __restrict__ W_hh,
                     const float* __restrict__ W_out, const float* __restrict__ b_out,
                     float* __restrict__ out)
{
    const int tid = threadIdx.x;
    const int kb  = tid & 15;
    const int jg  = tid >> 4;                 // 0..31
    const int r   = blockIdx.x;

    __shared__ __align__(16) float hs[2][16 * 36];   // padded chunks, 4.6 KB

    float4 wa[8][4];
#pragma unroll
    for (int a = 0; a < 8; ++a) {
        const float* wr = W_hh + (size_t)(jg * 8 + a) * H_ + kb * 16;
#pragma unroll
        for (int c4 = 0; c4 < 4; ++c4)
            wa[a][c4] = reinterpret_cast<const float4*>(wr)[c4];
    }
    float4 wo[2][4];
#pragma unroll
    for (int d = 0; d < 2; ++d) {
        const float* wr = W_out + (size_t)(jg * 2 + d) * H_ + kb * 16;
#pragma unroll
        for (int c4 = 0; c4 < 4; ++c4)
            wo[d][c4] = reinterpret_cast<const float4*>(wr)[c4];
    }
    const float2 bo = reinterpret_cast<const float2*>(b_out)[jg];

    const float* xwrow = xw + (size_t)r * T_ * H_;
    float* outrow = out + (size_t)r * T_ * O_;
    // physical base of this lane's j-block inside a padded hs buffer
    const int woff = (jg >> 1) * 36 + (jg & 1) * 8;

    float4 xwc0 = make_float4(0,0,0,0), xwc1 = xwc0;  // xw[t] (kb==0 lanes)
    float4 xn0 = xwc0, xn1 = xwc0;                    // xw[t+1]

    // ---- peel t=0: h_0 = relu(xw_0) ----
    if (kb == 0) {
        const float4* xp = reinterpret_cast<const float4*>(xwrow + jg * 8);
        float4 v0 = xp[0], v1 = xp[1];
        float4* hp = reinterpret_cast<float4*>(&hs[0][woff]);
        hp[0] = make_float4(fmaxf(v0.x,0.f), fmaxf(v0.y,0.f), fmaxf(v0.z,0.f), fmaxf(v0.w,0.f));
        hp[1] = make_float4(fmaxf(v1.x,0.f), fmaxf(v1.y,0.f), fmaxf(v1.z,0.f), fmaxf(v1.w,0.f));
        const float4* x1p = reinterpret_cast<const float4*>(xwrow + H_ + jg * 8);
        xwc0 = x1p[0]; xwc1 = x1p[1];                 // xw[1]
    }
    __syncthreads();

    float4 hr[4];
    {
        const float4* hp4 = reinterpret_cast<const float4*>(&hs[0][kb * 36]);
#pragma unroll
        for (int c4 = 0; c4 < 4; ++c4) hr[c4] = hp4[c4];
    }

#pragma unroll 1
    for (int t = 1; t < T_; ++t) {
        if (kb == 0) {                         // prefetch xw[t+1] (depth 2)
            const int tt = (t + 1 < T_) ? t + 1 : T_ - 1;
            const float4* xp = reinterpret_cast<const float4*>(
                xwrow + (size_t)tt * H_ + jg * 8);
            xn0 = xp[0]; xn1 = xp[1];
        }

        float acc[8];
#pragma unroll
        for (int a = 0; a < 8; ++a) acc[a] = 0.f;
        float oa0 = 0.f, oa1 = 0.f;
#pragma unroll
        for (int c4 = 0; c4 < 4; ++c4) {
            const float4 hv = hr[c4];
#pragma unroll
            for (int a = 0; a < 8; ++a) acc[a] = fma4(wa[a][c4], hv, acc[a]);
            oa0 = fma4(wo[0][c4], hv, oa0);
            oa1 = fma4(wo[1][c4], hv, oa1);
        }
#pragma unroll
        for (int a = 0; a < 8; ++a) acc[a] = reduce16(acc[a]);
        oa0 = reduce16(oa0);
        oa1 = reduce16(oa1);

        if (kb == 0) {
            float4* hp = reinterpret_cast<float4*>(&hs[t & 1][woff]);
            hp[0] = make_float4(fmaxf(acc[0]+xwc0.x,0.f), fmaxf(acc[1]+xwc0.y,0.f),
                                fmaxf(acc[2]+xwc0.z,0.f), fmaxf(acc[3]+xwc0.w,0.f));
            hp[1] = make_float4(fmaxf(acc[4]+xwc1.x,0.f), fmaxf(acc[5]+xwc1.y,0.f),
                                fmaxf(acc[6]+xwc1.z,0.f), fmaxf(acc[7]+xwc1.w,0.f));
            reinterpret_cast<float2*>(outrow + (size_t)(t - 1) * O_)[jg] =
                make_float2(oa0 + bo.x, oa1 + bo.y);
            xwc0 = xn0; xwc1 = xn1;
        }
        __syncthreads();                       // single barrier per step

        {
            const float4* hp4 = reinterpret_cast<const float4*>(&hs[t & 1][kb * 36]);
#pragma unroll
            for (int c4 = 0; c4 < 4; ++c4) hr[c4] = hp4[c4];
        }
    }

    // ---- epilogue: out_{T-1} from hr = h_{T-1} ----
    {
        float oa0 = 0.f, oa1 = 0.f;
#pragma unroll
        for (int c4 = 0; c4 < 4; ++c4) {
            oa0 = fma4(wo[0][c4], hr[c4], oa0);
            oa1 = fma4(wo[1][c4], hr[c4], oa1);
        }
        oa0 = reduce16(oa0);
        oa1 = reduce16(oa1);
        if (kb == 0)
            reinterpret_cast<float2*>(outrow + (size_t)(T_ - 1) * O_)[jg] =
                make_float2(oa0 + bo.x, oa1 + bo.y);
    }
}

// ---------------------------------------------------------------------------
extern "C" void kernel_launch(void* const* d_in, const int* in_sizes, int n_in,
                              void* d_out, int out_size, void* d_ws, size_t ws_size,
                              hipStream_t stream)
{
    (void)in_sizes; (void)n_in; (void)out_size; (void)ws_size;
    const float* x     = (const float*)d_in[0];   // [B,T,I]
    const float* W_xh  = (const float*)d_in[1];   // [H,I]
    const float* W_hh  = (const float*)d_in[2];   // [H,H]
    const float* b_h   = (const float*)d_in[3];   // [H]
    const float* W_out = (const float*)d_in[4];   // [O,H]
    const float* b_out = (const float*)d_in[5];   // [O]
    float* out = (float*)d_out;                   // [B,T,O]
    float* xw  = (float*)d_ws;                    // [B*T*H] fp32 = 128 MiB scratch

    xw_gemm_kernel<<<512, 256, 0, stream>>>(x, W_xh, b_h, xw);
    rnn_scan_kernel<<<128, 512, 0, stream>>>(xw, W_hh, W_out, b_out, out);
}

// Round 4
// 902.652 us; speedup vs baseline: 1.6236x; 1.6236x over previous
//
#include <hip/hip_runtime.h>

#define B_ 128
#define T_ 1024
#define I_ 128
#define H_ 256
#define O_ 64

// Force a float4's components to stay in VGPRs (defeats rematerialization /
// loop-sinking of loop-invariant weight loads).
#define PIN4(v) asm volatile("" : "+v"((v).x), "+v"((v).y), "+v"((v).z), "+v"((v).w))

__device__ __forceinline__ float fma4(float4 w, float4 h, float a) {
    a = fmaf(w.x, h.x, a); a = fmaf(w.y, h.y, a);
    a = fmaf(w.z, h.z, a); a = fmaf(w.w, h.w, a);
    return a;
}

// ---------------------------------------------------------------------------
// Phase A: xw[row,j] = sum_i x[row,i]*W_xh[j,i] + b_h[j]
// 512 WGs x 256 thr (2 WG/CU). lane (jb=tid&31, kb=tid>>5 in [0,8)) owns
// j in [jb*8,+8) x i in [kb*16,+16): W_xh tile = 128 VGPRs, PINNED.
// 8-row batches: phase1 writes 8 rows of partials into a 64x264 LDS buffer
// (XOR-swizzled), one barrier, phase2 reduces 64 b32 reads/lane and stores
// 8 coalesced rows. 2 barriers per 8 rows.
// ---------------------------------------------------------------------------
__global__ __launch_bounds__(256, 2)
void xw_gemm_kernel(const float* __restrict__ x, const float* __restrict__ W_xh,
                    const float* __restrict__ b_h, float* __restrict__ xw)
{
    const int tid = threadIdx.x;
    const int jb  = tid & 31;
    const int kb  = tid >> 5;                       // 0..7
    __shared__ __align__(16) float xs[2][8 * I_];   // 2 x 4 KB
    __shared__ __align__(16) float part[64 * 264];  // 66 KB, 8 rows x 8 kg

    float4 w[8][4];                                 // W_xh[jb*8+a][kb*16+c]
#pragma unroll
    for (int a = 0; a < 8; ++a) {
        const float* wr = W_xh + (size_t)(jb * 8 + a) * I_ + kb * 16;
#pragma unroll
        for (int c4 = 0; c4 < 4; ++c4) {
            w[a][c4] = reinterpret_cast<const float4*>(wr)[c4];
            PIN4(w[a][c4]);
        }
    }
    const float bh = b_h[tid];

    const int base = blockIdx.x * 256;              // 256 rows per WG
    {   // stage tile 0 (8 rows x 128 = 1024 floats = 256 float4)
        const float4* xp = reinterpret_cast<const float4*>(x + (size_t)base * I_);
        reinterpret_cast<float4*>(xs[0])[tid] = xp[tid];
    }
    __syncthreads();

    int buf = 0;
    for (int tile = 0; tile < 32; ++tile) {
        float4 pre = make_float4(0.f, 0.f, 0.f, 0.f);
        if (tile + 1 < 32) {
            const float4* xp = reinterpret_cast<const float4*>(
                x + (size_t)(base + (tile + 1) * 8) * I_);
            pre = xp[tid];
        }

        float4* p4 = reinterpret_cast<float4*>(part);
#pragma unroll 1
        for (int r = 0; r < 8; ++r) {
            const float4* xr = reinterpret_cast<const float4*>(
                xs[buf] + r * I_ + kb * 16);        // broadcast reads
            float acc[8];
#pragma unroll
            for (int a = 0; a < 8; ++a) acc[a] = 0.f;
#pragma unroll
            for (int c4 = 0; c4 < 4; ++c4) {
                const float4 xv = xr[c4];
#pragma unroll
                for (int a = 0; a < 8; ++a) acc[a] = fma4(w[a][c4], xv, acc[a]);
            }
            // row-stride 264 floats (66 float4); XOR swizzle col4 ^ kb
            const int rowb = (kb * 8 + r) * 66;
            p4[rowb + ((jb * 2 + 0) ^ kb)] = make_float4(acc[0], acc[1], acc[2], acc[3]);
            p4[rowb + ((jb * 2 + 1) ^ kb)] = make_float4(acc[4], acc[5], acc[6], acc[7]);
        }
        __syncthreads();                            // partials ready, xs[buf] free

        {   // phase2: lane j=tid reduces 8 rows x 8 groups
            const int q = tid >> 2, m = tid & 3;
            float* orow = xw + (size_t)(base + tile * 8) * H_ + tid;
#pragma unroll
            for (int r = 0; r < 8; ++r) {
                float s = 0.f;
#pragma unroll
                for (int g = 0; g < 8; ++g)
                    s += part[(g * 8 + r) * 264 + (((q ^ g) << 2) | m)];
                orow[(size_t)r * H_] = s + bh;
            }
        }
        if (tile + 1 < 32)
            reinterpret_cast<float4*>(xs[buf ^ 1])[tid] = pre;
        __syncthreads();                            // part free for next tile
        buf ^= 1;
    }
}

// ---------------------------------------------------------------------------
// Phase B: fused recurrence + out-projection (R2 structure, weights PINNED).
// 128 WGs x 512 thr, one per batch row. lane (jb=tid&31, kb=tid>>5 in [0,16))
// owns W_hh[jb*8+a][kb*16+c] (128 VGPR, pinned) and W_out[jb*2+d][kb*16+c]
// (32 VGPR, pinned).
//   phase 1 (all 8 waves): recurrence fmacs -> part (swizzled, stride 264);
//                          out-proj fmacs on h_{t-1} -> opart
//   barrier
//   phase 2: waves 0-3 reduce part(+xw,relu) -> hs; wave 4 reduces opart ->
//            global store out_{t-1} (concurrent)
//   barrier
//   all: hr <- hs (broadcast b128 reads, conflict-free)
// ---------------------------------------------------------------------------
__global__ __launch_bounds__(512, 2)
void rnn_scan_kernel(const float* __restrict__ xw, const float* __restrict__ W_hh,
                     const float* __restrict__ W_out, const float* __restrict__ b_out,
                     float* __restrict__ out)
{
    const int tid = threadIdx.x;
    const int jb  = tid & 31;
    const int kb  = tid >> 5;                 // 0..15
    const int r   = blockIdx.x;               // batch row

    __shared__ __align__(16) float hs[H_];
    __shared__ __align__(16) float part[16 * 264];   // 16.9 KB, swizzled
    __shared__ __align__(16) float opart[16 * 64];

    float4 wa[8][4];
#pragma unroll
    for (int a = 0; a < 8; ++a) {
        const float* wr = W_hh + (size_t)(jb * 8 + a) * H_ + kb * 16;
#pragma unroll
        for (int c4 = 0; c4 < 4; ++c4) {
            wa[a][c4] = reinterpret_cast<const float4*>(wr)[c4];
            PIN4(wa[a][c4]);
        }
    }
    float4 wo[2][4];
#pragma unroll
    for (int d = 0; d < 2; ++d) {
        const float* wr = W_out + (size_t)(jb * 2 + d) * H_ + kb * 16;
#pragma unroll
        for (int c4 = 0; c4 < 4; ++c4) {
            wo[d][c4] = reinterpret_cast<const float4*>(wr)[c4];
            PIN4(wo[d][c4]);
        }
    }

    const float* xwrow = xw + (size_t)r * T_ * H_;
    float* outrow = out + (size_t)r * T_ * O_;
    const float bo = (tid >= 256 && tid < 320) ? b_out[tid - 256] : 0.f;

    // ---- peel t=0: h_0 = relu(xw_0) ----
    float xwreg = 0.f, xwn1 = 0.f, xwn2 = 0.f;
    if (tid < 256) {
        hs[tid] = fmaxf(xwrow[tid], 0.f);
        xwreg = xwrow[(size_t)1 * H_ + tid];
        xwn1  = xwrow[(size_t)2 * H_ + tid];
    }
    __syncthreads();

    float4 hr[4];
    {
        const float4* hs4 = reinterpret_cast<const float4*>(hs);
#pragma unroll
        for (int c4 = 0; c4 < 4; ++c4) hr[c4] = hs4[kb * 4 + c4];
    }

#pragma unroll 1
    for (int t = 1; t < T_; ++t) {
        if (tid < 256) {                      // prefetch xw[t+2]
            const int tt = (t + 2 < T_) ? (t + 2) : (T_ - 1);
            xwn2 = xwrow[(size_t)tt * H_ + tid];
        }

        // --- phase 1: recurrence + out-proj fmacs ---
        float acc[8];
#pragma unroll
        for (int a = 0; a < 8; ++a) acc[a] = 0.f;
        float oa0 = 0.f, oa1 = 0.f;
#pragma unroll
        for (int c4 = 0; c4 < 4; ++c4) {
            const float4 hv = hr[c4];
#pragma unroll
            for (int a = 0; a < 8; ++a) acc[a] = fma4(wa[a][c4], hv, acc[a]);
            oa0 = fma4(wo[0][c4], hv, oa0);
            oa1 = fma4(wo[1][c4], hv, oa1);
        }
        {   // swizzled partial writes, row-stride 264 (66 float4)
            float4* p4 = reinterpret_cast<float4*>(part);
            p4[kb * 66 + ((jb * 2 + 0) ^ kb)] = make_float4(acc[0], acc[1], acc[2], acc[3]);
            p4[kb * 66 + ((jb * 2 + 1) ^ kb)] = make_float4(acc[4], acc[5], acc[6], acc[7]);
            reinterpret_cast<float2*>(opart)[kb * 32 + jb] = make_float2(oa0, oa1);
        }
        __syncthreads();                      // (1)

        // --- phase 2: concurrent reductions ---
        if (tid < 256) {                      // waves 0-3: h_t
            const int q = tid >> 2, m = tid & 3;
            float s = 0.f;
#pragma unroll
            for (int g = 0; g < 16; ++g)
                s += part[g * 264 + (((q ^ g) << 2) | m)];
            s += xwreg;
            hs[tid] = (s > 0.f) ? s : 0.f;
            xwreg = xwn1; xwn1 = xwn2;
        } else if (tid < 320) {               // wave 4: out_{t-1}
            const int to = tid - 256;
            float s = 0.f;
#pragma unroll
            for (int g = 0; g < 16; ++g) s += opart[g * 64 + to];
            outrow[(size_t)(t - 1) * O_ + to] = s + bo;
        }
        __syncthreads();                      // (2)

        {   // hr <- h_t (2 distinct addrs per wave -> broadcast, free)
            const float4* hs4 = reinterpret_cast<const float4*>(hs);
#pragma unroll
            for (int c4 = 0; c4 < 4; ++c4) hr[c4] = hs4[kb * 4 + c4];
        }
    }

    // ---- epilogue: out_{T-1} ----
    {
        float oa0 = 0.f, oa1 = 0.f;
#pragma unroll
        for (int c4 = 0; c4 < 4; ++c4) {
            oa0 = fma4(wo[0][c4], hr[c4], oa0);
            oa1 = fma4(wo[1][c4], hr[c4], oa1);
        }
        reinterpret_cast<float2*>(opart)[kb * 32 + jb] = make_float2(oa0, oa1);
        __syncthreads();
        if (tid >= 256 && tid < 320) {
            const int to = tid - 256;
            float s = 0.f;
#pragma unroll
            for (int g = 0; g < 16; ++g) s += opart[g * 64 + to];
            outrow[(size_t)(T_ - 1) * O_ + to] = s + bo;
        }
    }
}

// ---------------------------------------------------------------------------
extern "C" void kernel_launch(void* const* d_in, const int* in_sizes, int n_in,
                              void* d_out, int out_size, void* d_ws, size_t ws_size,
                              hipStream_t stream)
{
    (void)in_sizes; (void)n_in; (void)out_size; (void)ws_size;
    const float* x     = (const float*)d_in[0];   // [B,T,I]
    const float* W_xh  = (const float*)d_in[1];   // [H,I]
    const float* W_hh  = (const float*)d_in[2];   // [H,H]
    const float* b_h   = (const float*)d_in[3];   // [H]
    const float* W_out = (const float*)d_in[4];   // [O,H]
    const float* b_out = (const float*)d_in[5];   // [O]
    float* out = (float*)d_out;                   // [B,T,O]
    float* xw  = (float*)d_ws;                    // [B*T*H] fp32 = 128 MiB scratch

    xw_gemm_kernel<<<512, 256, 0, stream>>>(x, W_xh, b_h, xw);
    rnn_scan_kernel<<<128, 512, 0, stream>>>(xw, W_hh, W_out, b_out, out);
}